// Round 1
// baseline (252.808 us; speedup 1.0000x reference)
//
#include <hip/hip_runtime.h>

// CNOT (dim=2, wires=12, control=0, target=1) on x: (4096, 8192) f32.
//
// U @ x for this U is a row permutation: out[i, :] = x[i ^ (((i>>11)&1)<<10), :]
// (flip bit 10 of the row index iff bit 11 is set; involution).
// Pure streaming copy: 128 MiB read + 128 MiB write, zero FLOPs.
// Roofline: 268.4 MB at 6.29 TB/s (m13 achievable copy BW) = ~43 us.
//
// R4: drop __builtin_nontemporal_* — plain global_load/store_dwordx4,
// matching the 6.29 TB/s float4-copy microbenchmark pattern. Theory: the
// nt cache flag was costing ~2x (kernel residual ~82 us = 3.3 TB/s vs
// harness fills at 6.6 TB/s with plain stores). Structure unchanged:
// each block owns 1024 consecutive float4 (16 KiB) of one output row;
// each thread moves 4 float4 strided by 256 lanes -> every access is a
// contiguous 1 KiB wave transaction, 4 loads in flight before first store.

typedef float v4f __attribute__((ext_vector_type(4)));

#define NROWS 4096
#define ROW_F4 2048            // 8192 floats / 4 per row
#define BLK_F4 1024            // float4 per block
#define BLOCKS (NROWS * ROW_F4 / BLK_F4)   // 8192

__global__ __launch_bounds__(256) void cnot_perm_kernel(
    const v4f* __restrict__ x, v4f* __restrict__ out) {
    const int row  = blockIdx.x >> 1;            // 2 blocks per row
    const int half = (blockIdx.x & 1) << 10;     // 0 or 1024
    const int src  = row ^ (((row >> 11) & 1) << 10);

    const v4f* sp = x   + ((size_t)src << 11) + half + threadIdx.x;
    v4f*       dp = out + ((size_t)row << 11) + half + threadIdx.x;

    v4f a0 = sp[0];
    v4f a1 = sp[256];
    v4f a2 = sp[512];
    v4f a3 = sp[768];
    dp[0]   = a0;
    dp[256] = a1;
    dp[512] = a2;
    dp[768] = a3;
}

extern "C" void kernel_launch(void* const* d_in, const int* in_sizes, int n_in,
                              void* d_out, int out_size, void* d_ws, size_t ws_size,
                              hipStream_t stream) {
    // d_in[0] = U (4096x4096 f32, never read), d_in[1] = x (4096x8192 f32)
    const v4f* x = (const v4f*)d_in[1];
    v4f* out = (v4f*)d_out;
    cnot_perm_kernel<<<BLOCKS, 256, 0, stream>>>(x, out);
}